// Round 4
// baseline (745.160 us; speedup 1.0000x reference)
//
#include <hip/hip_runtime.h>

#define N_NODES 50000
#define N_EDGES 800000
#define D 128
#define C_OUT 10
#define BN_EPS 1e-5f

typedef unsigned int uint32;

__device__ __forceinline__ float bf2f(unsigned int u16) {
    unsigned int x = u16 << 16;
    float f;
    __builtin_memcpy(&f, &x, 4);
    return f;
}
__device__ __forceinline__ unsigned int f2bf(float f) {
    unsigned int x;
    __builtin_memcpy(&x, &f, 4);
    unsigned int r = x + 0x7FFFu + ((x >> 16) & 1u);  // RNE
    return r >> 16;
}
__device__ __forceinline__ uint32 pack_bf2(float a, float b) {
    return f2bf(a) | (f2bf(b) << 16);
}

// ---------------- adjacency build: per-destination linked list ----------------
// No CSR permutation (random 4B scatter = 16x HBM write amplification, R3 evidence).
// next[] is written SEQUENTIALLY; only the 200KB head/deg arrays take atomics.

__global__ void k_init(int* deg, int* head, float* sums) {
    int i = blockIdx.x * blockDim.x + threadIdx.x;
    if (i < N_NODES) { deg[i] = 1; head[i] = -1; }  // deg=1: self loop
    if (i < 768) sums[i] = 0.0f;                    // 3 layers x (sum|sumsq)
}

__global__ void k_link(const int* __restrict__ ei, int* __restrict__ deg,
                       int* __restrict__ head, int* __restrict__ next) {
    int e = blockIdx.x * blockDim.x + threadIdx.x;
    if (e >= N_EDGES) return;
    int d = ei[N_EDGES + e];                 // destination (col)
    atomicAdd(&deg[d], 1);
    int old = atomicExch(&head[d], e);
    next[e] = old;                           // sequential 3.2MB stream
}

__global__ void k_dinv(const int* __restrict__ deg, float* __restrict__ dinv) {
    int i = blockIdx.x * blockDim.x + threadIdx.x;
    if (i < N_NODES) dinv[i] = rsqrtf((float)deg[i]);
}

// ---------------- GEMM: hl[M,128](bf16, pre-scaled by dinv) = bnrelu(A) @ W ----------------
// BN finalize folded into prologue (sums -> scl/shl in LDS); sums==null => raw A (layer 1).

__global__ __launch_bounds__(256) void k_gemm(const float* __restrict__ A,
                                              const float* __restrict__ W,
                                              unsigned short* __restrict__ hl,
                                              const float* __restrict__ sums,
                                              const float* __restrict__ g,
                                              const float* __restrict__ be,
                                              const float* __restrict__ dinvp) {
    __shared__ float As[64 * 68];    // 64 rows x 64 k, pad stride 68
    __shared__ float Ws[64 * 128];   // 64 k x 128 cols
    __shared__ float scl[128], shl[128];
    int tid = threadIdx.x;
    int row0 = blockIdx.x * 64;

    if (sums && tid < 128) {
        float mean = sums[tid] * (1.0f / N_NODES);
        float var = fmaxf(sums[128 + tid] * (1.0f / N_NODES) - mean * mean, 0.f);
        float s = g[tid] * rsqrtf(var + BN_EPS);
        scl[tid] = s;
        shl[tid] = be[tid] - mean * s;
    }
    __syncthreads();

    const float4* A4 = (const float4*)A;
    const float4* W4 = (const float4*)W;
    float4* Ws4 = (float4*)Ws;

    int tc = (tid & 15) * 8;   // 16 col-groups of 8
    int tr = (tid >> 4) * 4;   // 16 row-groups of 4

    float acc[4][8];
#pragma unroll
    for (int i = 0; i < 4; ++i)
#pragma unroll
        for (int j = 0; j < 8; ++j) acc[i][j] = 0.f;

    for (int kc = 0; kc < 2; ++kc) {
#pragma unroll
        for (int it = 0; it < 8; ++it)
            Ws4[it * 256 + tid] = W4[kc * 2048 + it * 256 + tid];
#pragma unroll
        for (int it = 0; it < 4; ++it) {
            int f4 = it * 256 + tid;     // 0..1023
            int r = f4 >> 4;             // 16 float4 per row
            int c4 = f4 & 15;
            float4 v = make_float4(0.f, 0.f, 0.f, 0.f);
            int gr = row0 + r;
            if (gr < N_NODES) v = A4[(size_t)gr * 32 + kc * 16 + c4];
            if (sums) {  // fused BN + ReLU of previous layer
                float4 s = *(float4*)&scl[(kc * 16 + c4) * 4];
                float4 t = *(float4*)&shl[(kc * 16 + c4) * 4];
                v.x = fmaxf(v.x * s.x + t.x, 0.f);
                v.y = fmaxf(v.y * s.y + t.y, 0.f);
                v.z = fmaxf(v.z * s.z + t.z, 0.f);
                v.w = fmaxf(v.w * s.w + t.w, 0.f);
            }
            *(float4*)&As[r * 68 + c4 * 4] = v;
        }
        __syncthreads();
#pragma unroll 4
        for (int k = 0; k < 64; ++k) {
            float a[4] = {As[(tr + 0) * 68 + k], As[(tr + 1) * 68 + k],
                          As[(tr + 2) * 68 + k], As[(tr + 3) * 68 + k]};
            float4 b0 = *(float4*)&Ws[k * 128 + tc];
            float4 b1 = *(float4*)&Ws[k * 128 + tc + 4];
            float b[8] = {b0.x, b0.y, b0.z, b0.w, b1.x, b1.y, b1.z, b1.w};
#pragma unroll
            for (int i = 0; i < 4; ++i)
#pragma unroll
                for (int j = 0; j < 8; ++j) acc[i][j] += a[i] * b[j];
        }
        __syncthreads();
    }

#pragma unroll
    for (int i = 0; i < 4; ++i) {
        int r = row0 + tr + i;
        if (r < N_NODES) {
            float di = dinvp[r];  // pre-scale row by dinv[src]
            uint4 o;
            o.x = pack_bf2(acc[i][0] * di, acc[i][1] * di);
            o.y = pack_bf2(acc[i][2] * di, acc[i][3] * di);
            o.z = pack_bf2(acc[i][4] * di, acc[i][5] * di);
            o.w = pack_bf2(acc[i][6] * di, acc[i][7] * di);
            *(uint4*)&hl[(size_t)r * 128 + tc] = o;
        }
    }
}

// ---------------- Aggregation: one wave per node, walk incoming-edge chain ----------------
// Self loop seeds the accumulator (own hl row). Chain loads are wave-uniform; the
// hl row load (64 lanes x 4B) is the BW consumer, next/ei resolve from L2/L3.

__global__ void k_agg(const unsigned short* __restrict__ hl, const int* __restrict__ ei,
                      const int* __restrict__ head, const int* __restrict__ next,
                      const float* __restrict__ dinv, float* __restrict__ agg) {
    int node = (int)((blockIdx.x * blockDim.x + threadIdx.x) >> 6);
    int lane = threadIdx.x & 63;
    if (node >= N_NODES) return;
    uint32 p = *(const uint32*)&hl[(size_t)node * 128 + lane * 2];
    float ax = bf2f(p & 0xFFFFu);
    float ay = bf2f(p >> 16);
    int e = head[node];
    while (e >= 0) {
        int en = next[e];      // issue chain load first (overlaps hl fetch)
        int j = ei[e];         // source node
        uint32 q = *(const uint32*)&hl[(size_t)j * 128 + lane * 2];
        ax += bf2f(q & 0xFFFFu);
        ay += bf2f(q >> 16);
        e = en;
    }
    float di = dinv[node];
    *(float2*)&agg[(size_t)node * 128 + lane * 2] = make_float2(ax * di, ay * di);
}

// ---------------- BN stats ----------------

__global__ void k_bn_stats(const float* __restrict__ agg, float* __restrict__ sums) {
    __shared__ float sm[256];
    int tid = threadIdx.x;
    int c = tid & 127;
    float s = 0.f, q = 0.f;
    for (int r = blockIdx.x * 2 + (tid >> 7); r < N_NODES; r += gridDim.x * 2) {
        float v = agg[(size_t)r * 128 + c];
        s += v;
        q += v * v;
    }
    sm[tid] = s;
    __syncthreads();
    if (tid < 128) atomicAdd(&sums[c], sm[tid] + sm[tid + 128]);
    __syncthreads();
    sm[tid] = q;
    __syncthreads();
    if (tid < 128) atomicAdd(&sums[128 + c], sm[tid] + sm[tid + 128]);
}

// ---------------- Final readout: out (+)= bnrelu(h) @ Wf[base:base+128, :] ----------------
// BN finalize folded into prologue.

__global__ void k_out(const float* __restrict__ h, const float* __restrict__ Wf,
                      const float* __restrict__ bf, float* __restrict__ out,
                      int base, int addBias, const float* __restrict__ sums,
                      const float* __restrict__ g, const float* __restrict__ be) {
    __shared__ float Wl[128 * C_OUT];  // 5KB slice
    __shared__ float scl[128], shl[128];
    int tid = threadIdx.x;
    for (int i = tid; i < 128 * C_OUT; i += 256) Wl[i] = Wf[base * C_OUT + i];
    if (tid < 128) {
        float mean = sums[tid] * (1.0f / N_NODES);
        float var = fmaxf(sums[128 + tid] * (1.0f / N_NODES) - mean * mean, 0.f);
        float s = g[tid] * rsqrtf(var + BN_EPS);
        scl[tid] = s;
        shl[tid] = be[tid] - mean * s;
    }
    __syncthreads();
    int node = blockIdx.x * 4 + (tid >> 6);
    if (node >= N_NODES) return;
    int lane = tid & 63;
    float acc[C_OUT];
#pragma unroll
    for (int o = 0; o < C_OUT; ++o) acc[o] = 0.f;
#pragma unroll
    for (int t = 0; t < 128; t += 64) {
        int c = t + lane;
        float v = h[(size_t)node * 128 + c];
        v = fmaxf(v * scl[c] + shl[c], 0.f);  // fused BN + ReLU
#pragma unroll
        for (int o = 0; o < C_OUT; ++o) acc[o] += v * Wl[c * C_OUT + o];
    }
#pragma unroll
    for (int s = 32; s > 0; s >>= 1) {
#pragma unroll
        for (int o = 0; o < C_OUT; ++o) acc[o] += __shfl_down(acc[o], s, 64);
    }
    if (lane == 0) {
#pragma unroll
        for (int o = 0; o < C_OUT; ++o) {
            float r = acc[o] + (addBias ? bf[o] : out[(size_t)node * C_OUT + o]);
            out[(size_t)node * C_OUT + o] = r;
        }
    }
}

// ---------------- launch ----------------

extern "C" void kernel_launch(void* const* d_in, const int* in_sizes, int n_in,
                              void* d_out, int out_size, void* d_ws, size_t ws_size,
                              hipStream_t stream) {
    const float* x  = (const float*)d_in[0];
    const int*   ei = (const int*)d_in[1];   // [2,E] flat: [0:E)=row(src), [E:2E)=col(dst)
    const float* W1 = (const float*)d_in[2];
    const float* W2 = (const float*)d_in[4];
    const float* W3 = (const float*)d_in[6];
    // b1/b2/b3 (d_in[3,5,7]) absorbed exactly by BN mean-subtraction
    const float* g1  = (const float*)d_in[8];
    const float* be1 = (const float*)d_in[9];
    const float* g2  = (const float*)d_in[10];
    const float* be2 = (const float*)d_in[11];
    const float* g3  = (const float*)d_in[12];
    const float* be3 = (const float*)d_in[13];
    const float* Wf  = (const float*)d_in[14];
    const float* bf  = (const float*)d_in[15];
    float* out = (float*)d_out;

    char* ws = (char*)d_ws;
    size_t off = 0;
    auto alloc = [&](size_t bytes) -> void* {
        void* p = ws + off;
        off = (off + bytes + 255) & ~(size_t)255;
        return p;
    };
    int*   deg   = (int*)alloc((size_t)N_NODES * 4);
    int*   head  = (int*)alloc((size_t)N_NODES * 4);
    int*   next  = (int*)alloc((size_t)N_EDGES * 4);
    float* dinv  = (float*)alloc((size_t)N_NODES * 4);
    float* sums  = (float*)alloc(768 * 4);
    unsigned short* hl = (unsigned short*)alloc((size_t)N_NODES * 128 * 2);  // bf16
    float* bufA  = (float*)alloc((size_t)N_NODES * 128 * 4);
    float* bufB  = (float*)alloc((size_t)N_NODES * 128 * 4);

    const int TPB = 256;
    k_init<<<(N_NODES + TPB - 1) / TPB, TPB, 0, stream>>>(deg, head, sums);
    k_link<<<(N_EDGES + TPB - 1) / TPB, TPB, 0, stream>>>(ei, deg, head, next);
    k_dinv<<<(N_NODES + TPB - 1) / TPB, TPB, 0, stream>>>(deg, dinv);

    const int gemm_grid = (N_NODES + 63) / 64;          // 782
    const int agg_grid  = (N_NODES + 3) / 4;            // wave per node, 4/block
    const int out_grid  = (N_NODES + 3) / 4;

    // ---- layer 1 ----
    k_gemm<<<gemm_grid, 256, 0, stream>>>(x, W1, hl, nullptr, nullptr, nullptr, dinv);
    k_agg<<<agg_grid, 256, 0, stream>>>(hl, ei, head, next, dinv, bufA);
    k_bn_stats<<<512, 256, 0, stream>>>(bufA, sums + 0);
    k_out<<<out_grid, 256, 0, stream>>>(bufA, Wf, bf, out, 0, 1, sums + 0, g1, be1);

    // ---- layer 2 ----
    k_gemm<<<gemm_grid, 256, 0, stream>>>(bufA, W2, hl, sums + 0, g1, be1, dinv);
    k_agg<<<agg_grid, 256, 0, stream>>>(hl, ei, head, next, dinv, bufB);
    k_bn_stats<<<512, 256, 0, stream>>>(bufB, sums + 256);
    k_out<<<out_grid, 256, 0, stream>>>(bufB, Wf, bf, out, 128, 0, sums + 256, g2, be2);

    // ---- layer 3 ----
    k_gemm<<<gemm_grid, 256, 0, stream>>>(bufB, W3, hl, sums + 256, g2, be2, dinv);
    k_agg<<<agg_grid, 256, 0, stream>>>(hl, ei, head, next, dinv, bufA);
    k_bn_stats<<<512, 256, 0, stream>>>(bufA, sums + 512);
    k_out<<<out_grid, 256, 0, stream>>>(bufA, Wf, bf, out, 256, 0, sums + 512, g3, be3);
}

// Round 5
// 595.410 us; speedup vs baseline: 1.2515x; 1.2515x over previous
//
#include <hip/hip_runtime.h>

#define N_NODES 50000
#define N_EDGES 800000
#define D 128
#define C_OUT 10
#define BN_EPS 1e-5f
#define SCAN_BLOCKS 196   // ceil(50000/256)

typedef unsigned int uint32;
typedef __attribute__((ext_vector_type(8))) short bf16x8;
typedef __attribute__((ext_vector_type(4))) float f32x4;

__device__ __forceinline__ float bf2f(unsigned int u16) {
    unsigned int x = u16 << 16;
    float f;
    __builtin_memcpy(&f, &x, 4);
    return f;
}
__device__ __forceinline__ unsigned int f2bf(float f) {
    unsigned int x;
    __builtin_memcpy(&x, &f, 4);
    unsigned int r = x + 0x7FFFu + ((x >> 16) & 1u);  // RNE
    return r >> 16;
}
__device__ __forceinline__ uint32 pack_bf2(float a, float b) {
    return f2bf(a) | (f2bf(b) << 16);
}

// ---------------- CSR build (R3 structure: traverse-cost paid once) ----------------

__global__ void k_init(int* deg, float* sums) {
    int i = blockIdx.x * blockDim.x + threadIdx.x;
    if (i < N_NODES) deg[i] = 1;          // self loop
    if (i < 768) sums[i] = 0.0f;          // 3 layers x (sum|sumsq)
}

__global__ void k_count(const int* __restrict__ col, int* __restrict__ deg) {
    int e = blockIdx.x * blockDim.x + threadIdx.x;
    if (e < N_EDGES) atomicAdd(&deg[col[e]], 1);
}

__global__ __launch_bounds__(256) void k_scan1(const int* __restrict__ deg,
                                               int* __restrict__ offsets,
                                               int* __restrict__ blocksum,
                                               float* __restrict__ dinv) {
    __shared__ int sm[256];
    int tid = threadIdx.x;
    int i = blockIdx.x * 256 + tid;
    int v = (i < N_NODES) ? deg[i] : 0;
    if (i < N_NODES) dinv[i] = rsqrtf((float)v);
    sm[tid] = v;
    __syncthreads();
    for (int off = 1; off < 256; off <<= 1) {
        int t = (tid >= off) ? sm[tid - off] : 0;
        __syncthreads();
        sm[tid] += t;
        __syncthreads();
    }
    if (i < N_NODES) offsets[i] = sm[tid] - v;
    if (tid == 255) blocksum[blockIdx.x] = sm[255];
}

__global__ __launch_bounds__(256) void k_scan2(int* __restrict__ blocksum,
                                               int* __restrict__ offsets) {
    __shared__ int sm[256];
    int tid = threadIdx.x;
    int v = (tid < SCAN_BLOCKS) ? blocksum[tid] : 0;
    sm[tid] = v;
    __syncthreads();
    for (int off = 1; off < 256; off <<= 1) {
        int t = (tid >= off) ? sm[tid - off] : 0;
        __syncthreads();
        sm[tid] += t;
        __syncthreads();
    }
    if (tid < SCAN_BLOCKS) blocksum[tid] = sm[tid] - v;
    if (tid == 255) offsets[N_NODES] = sm[255];
}

__global__ __launch_bounds__(256) void k_scan3(int* __restrict__ offsets,
                                               const int* __restrict__ blocksum,
                                               int* __restrict__ cursor) {
    int i = blockIdx.x * 256 + threadIdx.x;
    if (i < N_NODES) {
        int o = offsets[i] + blocksum[blockIdx.x];
        offsets[i] = o;
        cursor[i] = o;
    }
}

__global__ void k_scatter(const int* __restrict__ ei, int* __restrict__ cursor,
                          int* __restrict__ csr_src) {
    int idx = blockIdx.x * blockDim.x + threadIdx.x;
    const int total = N_EDGES + N_NODES;
    if (idx >= total) return;
    int s, d;
    if (idx < N_EDGES) { s = ei[idx]; d = ei[N_EDGES + idx]; }
    else { s = idx - N_EDGES; d = s; }
    int p = atomicAdd(&cursor[d], 1);
    csr_src[p] = s;
}

// ---------------- W prep: fp32 [k][n] -> bf16 transposed [n][k] ----------------

__global__ void k_prep(const float* __restrict__ W1, const float* __restrict__ W2,
                       const float* __restrict__ W3, unsigned short* __restrict__ WT) {
    int mat = blockIdx.x >> 7;
    int n = blockIdx.x & 127;
    int k = threadIdx.x;  // 128 threads
    const float* W = (mat == 0) ? W1 : ((mat == 1) ? W2 : W3);
    WT[mat * 16384 + n * 128 + k] = (unsigned short)f2bf(W[k * 128 + n]);
}

// ---------------- MFMA GEMM: hl[M,128](bf16, row-scaled by dinv) = bnrelu(A) @ W ----
// Block tile 128x128, full K=128 single-stage. XOR swizzle (16B blocks, c^row&15):
// staging writes and frag reads both 2-way-conflict max (free on CDNA4).
// Wave w: rows w*32..w*32+31 (2 m-tiles), all 8 n-tiles: 64 MFMAs/wave.

__global__ __launch_bounds__(256) void k_gemm(const float* __restrict__ A,
                                              const unsigned short* __restrict__ WT,
                                              unsigned short* __restrict__ hl,
                                              const float* __restrict__ sums,
                                              const float* __restrict__ g,
                                              const float* __restrict__ be,
                                              const float* __restrict__ dinvp) {
    __shared__ unsigned short As[128 * 128];  // 32 KB
    __shared__ unsigned short Ws[128 * 128];  // 32 KB
    int tid = threadIdx.x;
    int row0 = blockIdx.x * 128;

    // per-thread BN scale/shift: this thread only stages columns cc..cc+3
    int cc = (tid & 31) * 4;
    float4 s4 = make_float4(1.f, 1.f, 1.f, 1.f);
    float4 t4 = make_float4(0.f, 0.f, 0.f, 0.f);
    if (sums) {
        float4 sm_ = *(const float4*)&sums[cc];
        float4 sq_ = *(const float4*)&sums[128 + cc];
        float4 gg = *(const float4*)&g[cc];
        float4 bb = *(const float4*)&be[cc];
        float m0 = sm_.x * (1.0f / N_NODES), m1 = sm_.y * (1.0f / N_NODES);
        float m2 = sm_.z * (1.0f / N_NODES), m3 = sm_.w * (1.0f / N_NODES);
        s4.x = gg.x * rsqrtf(fmaxf(sq_.x * (1.0f / N_NODES) - m0 * m0, 0.f) + BN_EPS);
        s4.y = gg.y * rsqrtf(fmaxf(sq_.y * (1.0f / N_NODES) - m1 * m1, 0.f) + BN_EPS);
        s4.z = gg.z * rsqrtf(fmaxf(sq_.z * (1.0f / N_NODES) - m2 * m2, 0.f) + BN_EPS);
        s4.w = gg.w * rsqrtf(fmaxf(sq_.w * (1.0f / N_NODES) - m3 * m3, 0.f) + BN_EPS);
        t4.x = bb.x - m0 * s4.x;  t4.y = bb.y - m1 * s4.y;
        t4.z = bb.z - m2 * s4.z;  t4.w = bb.w - m3 * s4.w;
    }

    // stage Ws (already transposed bf16 [n][k]); b64 chunks, swizzled write
    const ushort4* WT4 = (const ushort4*)WT;
#pragma unroll
    for (int i = 0; i < 16; ++i) {
        int idx = i * 256 + tid;            // [128 rows][32 chunks of 4 bf16]
        int r = idx >> 5, c4 = idx & 31;
        ushort4 v = WT4[idx];
        int swz = (c4 >> 1) ^ (r & 15);
        *(ushort4*)&Ws[r * 128 + swz * 8 + (c4 & 1) * 4] = v;
    }
    // stage As: fp32 read, optional BN+ReLU, cvt bf16, swizzled write
    const float4* A4 = (const float4*)A;
#pragma unroll
    for (int i = 0; i < 16; ++i) {
        int idx = i * 256 + tid;
        int r = idx >> 5, c4 = idx & 31;    // c4 == tid&31 for all i
        int gr = row0 + r;
        float4 v = make_float4(0.f, 0.f, 0.f, 0.f);
        if (gr < N_NODES) v = A4[(size_t)gr * 32 + c4];
        if (sums) {
            v.x = fmaxf(v.x * s4.x + t4.x, 0.f);
            v.y = fmaxf(v.y * s4.y + t4.y, 0.f);
            v.z = fmaxf(v.z * s4.z + t4.z, 0.f);
            v.w = fmaxf(v.w * s4.w + t4.w, 0.f);
        }
        ushort4 o;
        o.x = (unsigned short)f2bf(v.x);
        o.y = (unsigned short)f2bf(v.y);
        o.z = (unsigned short)f2bf(v.z);
        o.w = (unsigned short)f2bf(v.w);
        int swz = (c4 >> 1) ^ (r & 15);
        *(ushort4*)&As[r * 128 + swz * 8 + (c4 & 1) * 4] = o;
    }
    __syncthreads();

    int wave = tid >> 6, lane = tid & 63;
    int quad = lane >> 4, l16 = lane & 15;
    int m0 = wave * 32;

    // a-frags: A[m=lane&15][k=quad*8+j]; 2 m-tiles x 4 k-steps
    bf16x8 af[2][4];
#pragma unroll
    for (int mt = 0; mt < 2; ++mt) {
        int m = m0 + mt * 16 + l16;
#pragma unroll
        for (int ks = 0; ks < 4; ++ks) {
            int swz = (ks * 4 + quad) ^ (m & 15);
            af[mt][ks] = *(bf16x8*)&As[m * 128 + swz * 8];
        }
    }

    f32x4 acc[8][2];
#pragma unroll
    for (int nt = 0; nt < 8; ++nt)
#pragma unroll
        for (int mt = 0; mt < 2; ++mt) acc[nt][mt] = (f32x4){0.f, 0.f, 0.f, 0.f};

#pragma unroll
    for (int nt = 0; nt < 8; ++nt) {
        int n = nt * 16 + l16;
        bf16x8 bfr[4];
#pragma unroll
        for (int ks = 0; ks < 4; ++ks) {
            int swz = (ks * 4 + quad) ^ (n & 15);
            bfr[ks] = *(bf16x8*)&Ws[n * 128 + swz * 8];
        }
#pragma unroll
        for (int mt = 0; mt < 2; ++mt)
#pragma unroll
            for (int ks = 0; ks < 4; ++ks)
                acc[nt][mt] = __builtin_amdgcn_mfma_f32_16x16x32_bf16(
                    af[mt][ks], bfr[ks], acc[nt][mt], 0, 0, 0);
    }

    // C/D: col = lane&15, row = quad*4 + reg (m89-verified); scale by dinv, store bf16
#pragma unroll
    for (int mt = 0; mt < 2; ++mt) {
#pragma unroll
        for (int reg = 0; reg < 4; ++reg) {
            int m = row0 + m0 + mt * 16 + quad * 4 + reg;
            if (m < N_NODES) {
                float di = dinvp[m];
#pragma unroll
                for (int nt = 0; nt < 8; ++nt) {
                    int n = nt * 16 + l16;
                    hl[(size_t)m * 128 + n] = (unsigned short)f2bf(acc[nt][mt][reg] * di);
                }
            }
        }
    }
}

// ---------------- Aggregation: one wave per node, 2 bf16/lane, CSR ----------------

__global__ void k_agg(const unsigned short* __restrict__ hl, const int* __restrict__ csr_src,
                      const int* __restrict__ offsets, const float* __restrict__ dinv,
                      float* __restrict__ agg) {
    int node = (int)((blockIdx.x * blockDim.x + threadIdx.x) >> 6);
    int lane = threadIdx.x & 63;
    if (node >= N_NODES) return;
    int beg = offsets[node], end = offsets[node + 1];
    float ax = 0.f, ay = 0.f;
    int e = beg;
    for (; e + 1 < end; e += 2) {
        int j0 = csr_src[e];
        int j1 = csr_src[e + 1];
        uint32 p0 = *(const uint32*)&hl[(size_t)j0 * 128 + lane * 2];
        uint32 p1 = *(const uint32*)&hl[(size_t)j1 * 128 + lane * 2];
        ax += bf2f(p0 & 0xFFFFu) + bf2f(p1 & 0xFFFFu);
        ay += bf2f(p0 >> 16) + bf2f(p1 >> 16);
    }
    if (e < end) {
        int j = csr_src[e];
        uint32 p = *(const uint32*)&hl[(size_t)j * 128 + lane * 2];
        ax += bf2f(p & 0xFFFFu);
        ay += bf2f(p >> 16);
    }
    float di = dinv[node];
    *(float2*)&agg[(size_t)node * 128 + lane * 2] = make_float2(ax * di, ay * di);
}

// ---------------- BN stats ----------------

__global__ void k_bn_stats(const float* __restrict__ agg, float* __restrict__ sums) {
    __shared__ float sm[256];
    int tid = threadIdx.x;
    int c = tid & 127;
    float s = 0.f, q = 0.f;
    for (int r = blockIdx.x * 2 + (tid >> 7); r < N_NODES; r += gridDim.x * 2) {
        float v = agg[(size_t)r * 128 + c];
        s += v;
        q += v * v;
    }
    sm[tid] = s;
    __syncthreads();
    if (tid < 128) atomicAdd(&sums[c], sm[tid] + sm[tid + 128]);
    __syncthreads();
    sm[tid] = q;
    __syncthreads();
    if (tid < 128) atomicAdd(&sums[128 + c], sm[tid] + sm[tid + 128]);
}

// ---------------- Final readout: out (+)= bnrelu(h) @ Wf[base:base+128, :] ----------------

__global__ void k_out(const float* __restrict__ h, const float* __restrict__ Wf,
                      const float* __restrict__ bf, float* __restrict__ out,
                      int base, int addBias, const float* __restrict__ sums,
                      const float* __restrict__ g, const float* __restrict__ be) {
    __shared__ float Wl[128 * C_OUT];
    __shared__ float scl[128], shl[128];
    int tid = threadIdx.x;
    for (int i = tid; i < 128 * C_OUT; i += 256) Wl[i] = Wf[base * C_OUT + i];
    if (tid < 128) {
        float mean = sums[tid] * (1.0f / N_NODES);
        float var = fmaxf(sums[128 + tid] * (1.0f / N_NODES) - mean * mean, 0.f);
        float s = g[tid] * rsqrtf(var + BN_EPS);
        scl[tid] = s;
        shl[tid] = be[tid] - mean * s;
    }
    __syncthreads();
    int node = blockIdx.x * 4 + (tid >> 6);
    if (node >= N_NODES) return;
    int lane = tid & 63;
    float acc[C_OUT];
#pragma unroll
    for (int o = 0; o < C_OUT; ++o) acc[o] = 0.f;
#pragma unroll
    for (int t = 0; t < 128; t += 64) {
        int c = t + lane;
        float v = h[(size_t)node * 128 + c];
        v = fmaxf(v * scl[c] + shl[c], 0.f);
#pragma unroll
        for (int o = 0; o < C_OUT; ++o) acc[o] += v * Wl[c * C_OUT + o];
    }
#pragma unroll
    for (int s = 32; s > 0; s >>= 1) {
#pragma unroll
        for (int o = 0; o < C_OUT; ++o) acc[o] += __shfl_down(acc[o], s, 64);
    }
    if (lane == 0) {
#pragma unroll
        for (int o = 0; o < C_OUT; ++o) {
            float r = acc[o] + (addBias ? bf[o] : out[(size_t)node * C_OUT + o]);
            out[(size_t)node * C_OUT + o] = r;
        }
    }
}

// ---------------- launch ----------------

extern "C" void kernel_launch(void* const* d_in, const int* in_sizes, int n_in,
                              void* d_out, int out_size, void* d_ws, size_t ws_size,
                              hipStream_t stream) {
    const float* x  = (const float*)d_in[0];
    const int*   ei = (const int*)d_in[1];
    const float* W1 = (const float*)d_in[2];
    const float* W2 = (const float*)d_in[4];
    const float* W3 = (const float*)d_in[6];
    // b1/b2/b3 absorbed exactly by BN mean-subtraction
    const float* g1  = (const float*)d_in[8];
    const float* be1 = (const float*)d_in[9];
    const float* g2  = (const float*)d_in[10];
    const float* be2 = (const float*)d_in[11];
    const float* g3  = (const float*)d_in[12];
    const float* be3 = (const float*)d_in[13];
    const float* Wf  = (const float*)d_in[14];
    const float* bf  = (const float*)d_in[15];
    float* out = (float*)d_out;

    char* ws = (char*)d_ws;
    size_t off = 0;
    auto alloc = [&](size_t bytes) -> void* {
        void* p = ws + off;
        off = (off + bytes + 255) & ~(size_t)255;
        return p;
    };
    int*   deg      = (int*)alloc((size_t)N_NODES * 4);
    int*   offsets  = (int*)alloc((size_t)(N_NODES + 1) * 4);
    int*   cursor   = (int*)alloc((size_t)N_NODES * 4);
    int*   blocksum = (int*)alloc((size_t)SCAN_BLOCKS * 4);
    int*   csr_src  = (int*)alloc((size_t)(N_EDGES + N_NODES) * 4);
    float* dinv     = (float*)alloc((size_t)N_NODES * 4);
    float* sums     = (float*)alloc(768 * 4);
    unsigned short* WT = (unsigned short*)alloc((size_t)3 * 128 * 128 * 2);  // bf16 W^T x3
    unsigned short* hl = (unsigned short*)alloc((size_t)N_NODES * 128 * 2);  // bf16
    float* bufA    = (float*)alloc((size_t)N_NODES * 128 * 4);
    float* bufB    = (float*)alloc((size_t)N_NODES * 128 * 4);

    const int TPB = 256;
    k_prep<<<384, 128, 0, stream>>>(W1, W2, W3, WT);
    k_init<<<(N_NODES + TPB - 1) / TPB, TPB, 0, stream>>>(deg, sums);
    k_count<<<(N_EDGES + TPB - 1) / TPB, TPB, 0, stream>>>(ei + N_EDGES, deg);
    k_scan1<<<SCAN_BLOCKS, 256, 0, stream>>>(deg, offsets, blocksum, dinv);
    k_scan2<<<1, 256, 0, stream>>>(blocksum, offsets);
    k_scan3<<<SCAN_BLOCKS, 256, 0, stream>>>(offsets, blocksum, cursor);
    k_scatter<<<(N_EDGES + N_NODES + TPB - 1) / TPB, TPB, 0, stream>>>(ei, cursor, csr_src);

    const int gemm_grid = (N_NODES + 127) / 128;        // 391
    const int agg_grid  = (N_NODES + 3) / 4;
    const int out_grid  = (N_NODES + 3) / 4;

    // ---- layer 1 ----
    k_gemm<<<gemm_grid, 256, 0, stream>>>(x, WT, hl, nullptr, nullptr, nullptr, dinv);
    k_agg<<<agg_grid, 256, 0, stream>>>(hl, csr_src, offsets, dinv, bufA);
    k_bn_stats<<<512, 256, 0, stream>>>(bufA, sums + 0);
    k_out<<<out_grid, 256, 0, stream>>>(bufA, Wf, bf, out, 0, 1, sums + 0, g1, be1);

    // ---- layer 2 ----
    k_gemm<<<gemm_grid, 256, 0, stream>>>(bufA, WT + 16384, hl, sums + 0, g1, be1, dinv);
    k_agg<<<agg_grid, 256, 0, stream>>>(hl, csr_src, offsets, dinv, bufB);
    k_bn_stats<<<512, 256, 0, stream>>>(bufB, sums + 256);
    k_out<<<out_grid, 256, 0, stream>>>(bufB, Wf, bf, out, 128, 0, sums + 256, g2, be2);

    // ---- layer 3 ----
    k_gemm<<<gemm_grid, 256, 0, stream>>>(bufB, WT + 32768, hl, sums + 256, g2, be2, dinv);
    k_agg<<<agg_grid, 256, 0, stream>>>(hl, csr_src, offsets, dinv, bufA);
    k_bn_stats<<<512, 256, 0, stream>>>(bufA, sums + 512);
    k_out<<<out_grid, 256, 0, stream>>>(bufA, Wf, bf, out, 256, 0, sums + 512, g3, be3);
}